// Round 5
// baseline (55.213 us; speedup 1.0000x reference)
//
#include <hip/hip_runtime.h>

#define N 384
#define DXD 128
#define DZD 32
#define NORM (2.0f / 1443840.0f)   // 2 / (n*K*(2n-3K-1)), n=384, K=5

// Kernel 0: transpose X (384x128) -> XT (128x384), Z (384x32) -> ZT (32x384).
// Reads coalesced (k consecutive within row a); writes scalar/uncoalesced but tiny.
__global__ void __launch_bounds__(192) transpose_xz(const float* __restrict__ X,
                                                    const float* __restrict__ Z,
                                                    float* __restrict__ XT,
                                                    float* __restrict__ ZT) {
    const int a = blockIdx.x;
    const int k = threadIdx.x;
    if (k < DXD) XT[(size_t)k * N + a] = X[(size_t)a * DXD + k];
    else if (k < DXD + DZD) ZT[(size_t)(k - DXD) * N + a] = Z[(size_t)a * DZD + (k - DXD)];
}

// Kernel 1: E[i][a] = exp(2*||row_i - row_a||). Coalesced: lane -> a.
// Block (i, half): threads cover a = half*192 + t.
__global__ void __launch_bounds__(192) exp_rows2(const float* __restrict__ X,
                                                 const float* __restrict__ Z,
                                                 const float* __restrict__ XT,
                                                 const float* __restrict__ ZT,
                                                 float* __restrict__ EX,
                                                 float* __restrict__ EZ) {
    __shared__ float xi[DXD];
    __shared__ float zi[DZD];
    const int i = blockIdx.x >> 1;
    const int half = blockIdx.x & 1;
    const int t = threadIdx.x;
    const int a = half * 192 + t;

    if (t < DXD) xi[t] = X[(size_t)i * DXD + t];
    else if (t < DXD + DZD) zi[t - DXD] = Z[(size_t)i * DZD + (t - DXD)];
    __syncthreads();

    float sq = 0.f;
    #pragma unroll 8
    for (int k = 0; k < DXD; ++k) {
        float v = XT[(size_t)k * N + a] - xi[k];   // coalesced across lanes
        sq += v * v;
    }
    float dx = (sq > 1e-12f) ? sqrtf(sq) : 0.f;
    EX[(size_t)i * N + a] = __expf(2.f * dx);

    float sqz = 0.f;
    #pragma unroll 8
    for (int k = 0; k < DZD; ++k) {
        float v = ZT[(size_t)k * N + a] - zi[k];
        sqz += v * v;
    }
    float dz = (sqz > 1e-12f) ? sqrtf(sqz) : 0.f;
    EZ[(size_t)i * N + a] = __expf(2.f * dz);
}

// Kernel 2: block (chunk, i): 64 a-values (lane), 4 waves split b-range 4x96.
// sigmoid((d_b - d_a)/tau) = e_b / (e_b + e_a). Rows staged in LDS.
__global__ void __launch_bounds__(256) loss3(const float* __restrict__ EX,
                                             const float* __restrict__ EZ,
                                             float* __restrict__ out) {
    __shared__ float exs[N] __attribute__((aligned(16)));
    __shared__ float ezs[N] __attribute__((aligned(16)));
    __shared__ float sxs[4][64];
    __shared__ float szs[4][64];
    const int i = blockIdx.y;
    const int chunk = blockIdx.x;            // 0..5
    const int t = threadIdx.x;
    const int w = t >> 6, lane = t & 63;

    const float* __restrict__ exrow = EX + (size_t)i * N;
    const float* __restrict__ ezrow = EZ + (size_t)i * N;

    // stage both rows coalesced: 192 float4 loads
    if (t < 96)       reinterpret_cast<float4*>(exs)[t]      = reinterpret_cast<const float4*>(exrow)[t];
    else if (t < 192) reinterpret_cast<float4*>(ezs)[t - 96] = reinterpret_cast<const float4*>(ezrow)[t - 96];
    const float exa = exrow[chunk * 64 + lane];   // coalesced
    const float eza = ezrow[chunk * 64 + lane];
    __syncthreads();

    // wave w: b in [w*96, w*96+96) = 24 float4
    const float4* __restrict__ ex4 = reinterpret_cast<const float4*>(exs + w * 96);
    const float4* __restrict__ ez4 = reinterpret_cast<const float4*>(ezs + w * 96);
    float sx0 = 0.f, sx1 = 0.f, sx2 = 0.f, sx3 = 0.f;
    float sz0 = 0.f, sz1 = 0.f, sz2 = 0.f, sz3 = 0.f;
    #pragma unroll 4
    for (int b = 0; b < 24; ++b) {
        float4 e = ex4[b];                    // uniform -> LDS broadcast
        float4 f = ez4[b];
        sx0 += e.x * __builtin_amdgcn_rcpf(e.x + exa);
        sx1 += e.y * __builtin_amdgcn_rcpf(e.y + exa);
        sx2 += e.z * __builtin_amdgcn_rcpf(e.z + exa);
        sx3 += e.w * __builtin_amdgcn_rcpf(e.w + exa);
        sz0 += f.x * __builtin_amdgcn_rcpf(f.x + eza);
        sz1 += f.y * __builtin_amdgcn_rcpf(f.y + eza);
        sz2 += f.z * __builtin_amdgcn_rcpf(f.z + eza);
        sz3 += f.w * __builtin_amdgcn_rcpf(f.w + eza);
    }
    sxs[w][lane] = (sx0 + sx1) + (sx2 + sx3);
    szs[w][lane] = (sz0 + sz1) + (sz2 + sz3);
    __syncthreads();

    if (w == 0) {
        float sx = (sxs[0][lane] + sxs[1][lane]) + (sxs[2][lane] + sxs[3][lane]);
        float sz = (szs[0][lane] + szs[1][lane]) + (szs[2][lane] + szs[3][lane]);
        // intrusion = relu(1+sx-K); W = clamp((K+1-(1+sz))/K,0,1)
        float intr = fmaxf(sx - 4.f, 0.f);
        float W = fminf(fmaxf((5.f - sz) * 0.2f, 0.f), 1.f);
        float contrib = intr * (1.f - W);
        #pragma unroll
        for (int off = 32; off > 0; off >>= 1)
            contrib += __shfl_down(contrib, off, 64);
        if (lane == 0) atomicAdd(out, contrib * NORM);
    }
}

extern "C" void kernel_launch(void* const* d_in, const int* in_sizes, int n_in,
                              void* d_out, int out_size, void* d_ws, size_t ws_size,
                              hipStream_t stream) {
    const float* X = (const float*)d_in[0];   // (384, 128) f32
    const float* Z = (const float*)d_in[1];   // (384, 32)  f32
    float* out = (float*)d_out;

    float* XT = (float*)d_ws;                  // 128*384
    float* ZT = XT + (size_t)DXD * N;          // 32*384
    float* EX = ZT + (size_t)DZD * N;          // 384*384
    float* EZ = EX + (size_t)N * N;            // 384*384

    hipMemsetAsync(out, 0, sizeof(float), stream);
    transpose_xz<<<N, 192, 0, stream>>>(X, Z, XT, ZT);
    exp_rows2<<<2 * N, 192, 0, stream>>>(X, Z, XT, ZT, EX, EZ);
    loss3<<<dim3(6, N), 256, 0, stream>>>(EX, EZ, out);
}

// Round 9
// 38.674 us; speedup vs baseline: 1.4276x; 1.4276x over previous
//
#include <hip/hip_runtime.h>

#define N 384
#define DXD 128
#define DZD 32
#define NORM (2.0f / 1443840.0f)   // 2 / (n*K*(2n-3K-1)), n=384, K=5

// ---------------------------------------------------------------------------
// Kernel A: LDS-tiled transpose, coalesced on BOTH sides.
// Blocks 0..5: X stripes (64 rows x 128 cols) -> XT (128 x 384)
// Blocks 6..11: Z stripes (64 rows x 32 cols) -> ZT (32 x 384)
// Also zeroes out[0] (ordered before loss kernel's atomics).
__global__ void __launch_bounds__(256) transpose_xz(const float* __restrict__ X,
                                                    const float* __restrict__ Z,
                                                    float* __restrict__ XT,
                                                    float* __restrict__ ZT,
                                                    float* __restrict__ out) {
    __shared__ float tile[64][129];   // +1 pad: column reads conflict-free
    const int b = blockIdx.x;
    const int t = threadIdx.x;
    if (b == 0 && t == 0) out[0] = 0.f;

    if (b < 6) {
        const int R = b * 64;
        // load 64x128 coalesced: 8 rows per round (32 lanes x float4 per row)
        #pragma unroll
        for (int r0 = 0; r0 < 64; r0 += 8) {
            const int r = r0 + (t >> 5);
            const int c = (t & 31) * 4;
            float4 v = *reinterpret_cast<const float4*>(X + (size_t)(R + r) * DXD + c);
            tile[r][c] = v.x; tile[r][c + 1] = v.y; tile[r][c + 2] = v.z; tile[r][c + 3] = v.w;
        }
        __syncthreads();
        // write coalesced: wave-uniform k, lane -> a. lds read bank = (l + k) % 32: free
        const int l = t & 63, w = t >> 6;
        #pragma unroll
        for (int k0 = 0; k0 < DXD; k0 += 4) {
            const int k = k0 + w;
            XT[(size_t)k * N + R + l] = tile[l][k];
        }
    } else {
        const int R = (b - 6) * 64;
        // load 64x32 coalesced: 32 rows per round (8 lanes x float4 per row)
        #pragma unroll
        for (int r0 = 0; r0 < 64; r0 += 32) {
            const int r = r0 + (t >> 3);
            const int c = (t & 7) * 4;
            float4 v = *reinterpret_cast<const float4*>(Z + (size_t)(R + r) * DZD + c);
            tile[r][c] = v.x; tile[r][c + 1] = v.y; tile[r][c + 2] = v.z; tile[r][c + 3] = v.w;
        }
        __syncthreads();
        const int l = t & 63, w = t >> 6;
        #pragma unroll
        for (int k0 = 0; k0 < DZD; k0 += 4) {
            const int k = k0 + w;
            ZT[(size_t)k * N + R + l] = tile[l][k];
        }
    }
}

// ---------------------------------------------------------------------------
// Kernel B: E[i][a] = exp(2*||row_i - row_a||). XT reads coalesced (lane->a);
// X_i reads wave-uniform (scalar-cache / 1-line broadcast). No LDS.
__global__ void __launch_bounds__(192) exp_rows(const float* __restrict__ X,
                                                const float* __restrict__ Z,
                                                const float* __restrict__ XT,
                                                const float* __restrict__ ZT,
                                                float* __restrict__ EX,
                                                float* __restrict__ EZ) {
    const int i = blockIdx.x >> 1;
    const int a = (blockIdx.x & 1) * 192 + threadIdx.x;

    const float* __restrict__ Xi = X + (size_t)i * DXD;
    float sq = 0.f;
    #pragma unroll 8
    for (int k = 0; k < DXD; ++k) {
        float v = XT[(size_t)k * N + a] - Xi[k];
        sq += v * v;
    }
    float dx = (sq > 1e-12f) ? sqrtf(sq) : 0.f;
    EX[(size_t)i * N + a] = __expf(2.f * dx);

    const float* __restrict__ Zi = Z + (size_t)i * DZD;
    float sqz = 0.f;
    #pragma unroll 8
    for (int k = 0; k < DZD; ++k) {
        float v = ZT[(size_t)k * N + a] - Zi[k];
        sqz += v * v;
    }
    float dz = (sqz > 1e-12f) ? sqrtf(sqz) : 0.f;
    EZ[(size_t)i * N + a] = __expf(2.f * dz);
}

// ---------------------------------------------------------------------------
// Kernel C: loss. sigmoid((d_b - d_a)/tau) = e_b / (e_b + e_a).
// b-loop reads are wave-uniform GLOBAL float4 (1 cache line, no LDS pipe).
// 8 independent rcp chains for trans-pipe ILP. One atomic per block.
__global__ void __launch_bounds__(192) loss_k(const float* __restrict__ EX,
                                              const float* __restrict__ EZ,
                                              float* __restrict__ out) {
    __shared__ float red[3];
    const int i = blockIdx.x >> 1;
    const int t = threadIdx.x;
    const int a = (blockIdx.x & 1) * 192 + t;

    const float* __restrict__ exrow = EX + (size_t)i * N;
    const float* __restrict__ ezrow = EZ + (size_t)i * N;
    const float exa = exrow[a];    // coalesced per-lane
    const float eza = ezrow[a];

    const float4* __restrict__ ex4 = reinterpret_cast<const float4*>(exrow);
    const float4* __restrict__ ez4 = reinterpret_cast<const float4*>(ezrow);
    float sx0 = 0.f, sx1 = 0.f, sx2 = 0.f, sx3 = 0.f;
    float sz0 = 0.f, sz1 = 0.f, sz2 = 0.f, sz3 = 0.f;
    #pragma unroll 4
    for (int b = 0; b < N / 4; ++b) {
        float4 e = ex4[b];          // uniform -> single-line L1 broadcast
        float4 f = ez4[b];
        sx0 += e.x * __builtin_amdgcn_rcpf(e.x + exa);
        sx1 += e.y * __builtin_amdgcn_rcpf(e.y + exa);
        sx2 += e.z * __builtin_amdgcn_rcpf(e.z + exa);
        sx3 += e.w * __builtin_amdgcn_rcpf(e.w + exa);
        sz0 += f.x * __builtin_amdgcn_rcpf(f.x + eza);
        sz1 += f.y * __builtin_amdgcn_rcpf(f.y + eza);
        sz2 += f.z * __builtin_amdgcn_rcpf(f.z + eza);
        sz3 += f.w * __builtin_amdgcn_rcpf(f.w + eza);
    }
    float sx = (sx0 + sx1) + (sx2 + sx3);
    float sz = (sz0 + sz1) + (sz2 + sz3);

    // intrusion = relu(1+sx-K); W = clamp((K+1-(1+sz))/K, 0, 1)
    float intr = fmaxf(sx - 4.f, 0.f);
    float W = fminf(fmaxf((5.f - sz) * 0.2f, 0.f), 1.f);
    float contrib = intr * (1.f - W);

    #pragma unroll
    for (int off = 32; off > 0; off >>= 1)
        contrib += __shfl_down(contrib, off, 64);
    const int lane = t & 63, w = t >> 6;
    if (lane == 0) red[w] = contrib;
    __syncthreads();
    if (t == 0) atomicAdd(out, (red[0] + red[1] + red[2]) * NORM);
}

extern "C" void kernel_launch(void* const* d_in, const int* in_sizes, int n_in,
                              void* d_out, int out_size, void* d_ws, size_t ws_size,
                              hipStream_t stream) {
    const float* X = (const float*)d_in[0];   // (384, 128) f32
    const float* Z = (const float*)d_in[1];   // (384, 32)  f32
    float* out = (float*)d_out;

    float* XT = (float*)d_ws;                  // 128*384
    float* ZT = XT + (size_t)DXD * N;          // 32*384
    float* EX = ZT + (size_t)DZD * N;          // 384*384
    float* EZ = EX + (size_t)N * N;            // 384*384

    transpose_xz<<<12, 256, 0, stream>>>(X, Z, XT, ZT, out);
    exp_rows<<<2 * N, 192, 0, stream>>>(X, Z, XT, ZT, EX, EZ);
    loss_k<<<2 * N, 192, 0, stream>>>(EX, EZ, out);
}

// Round 10
// 38.138 us; speedup vs baseline: 1.4477x; 1.0141x over previous
//
#include <hip/hip_runtime.h>

#define N 384
#define DXD 128
#define DZD 32
#define NORM (2.0f / 1443840.0f)   // 2 / (n*K*(2n-3K-1)), n=384, K=5

// ---------------------------------------------------------------------------
// Kernel A: LDS-tiled transpose, coalesced on BOTH sides.
// Blocks 0..5: X stripes (64 rows x 128 cols) -> XT (128 x 384)
// Blocks 6..11: Z stripes (64 rows x 32 cols) -> ZT (32 x 384)
// Also zeroes out[0] (stream-ordered before kernel B's atomics).
__global__ void __launch_bounds__(256) transpose_xz(const float* __restrict__ X,
                                                    const float* __restrict__ Z,
                                                    float* __restrict__ XT,
                                                    float* __restrict__ ZT,
                                                    float* __restrict__ out) {
    __shared__ float tile[64][129];   // +1 pad: column reads conflict-free
    const int b = blockIdx.x;
    const int t = threadIdx.x;
    if (b == 0 && t == 0) out[0] = 0.f;

    if (b < 6) {
        const int R = b * 64;
        #pragma unroll
        for (int r0 = 0; r0 < 64; r0 += 8) {
            const int r = r0 + (t >> 5);
            const int c = (t & 31) * 4;
            float4 v = *reinterpret_cast<const float4*>(X + (size_t)(R + r) * DXD + c);
            tile[r][c] = v.x; tile[r][c + 1] = v.y; tile[r][c + 2] = v.z; tile[r][c + 3] = v.w;
        }
        __syncthreads();
        const int l = t & 63, w = t >> 6;
        #pragma unroll
        for (int k0 = 0; k0 < DXD; k0 += 4) {
            const int k = k0 + w;
            XT[(size_t)k * N + R + l] = tile[l][k];
        }
    } else {
        const int R = (b - 6) * 64;
        #pragma unroll
        for (int r0 = 0; r0 < 64; r0 += 32) {
            const int r = r0 + (t >> 3);
            const int c = (t & 7) * 4;
            float4 v = *reinterpret_cast<const float4*>(Z + (size_t)(R + r) * DZD + c);
            tile[r][c] = v.x; tile[r][c + 1] = v.y; tile[r][c + 2] = v.z; tile[r][c + 3] = v.w;
        }
        __syncthreads();
        const int l = t & 63, w = t >> 6;
        #pragma unroll
        for (int k0 = 0; k0 < DZD; k0 += 4) {
            const int k = k0 + w;
            ZT[(size_t)k * N + R + l] = tile[l][k];
        }
    }
}

// ---------------------------------------------------------------------------
// Kernel B: fully fused per-row loss. Block (i, half): compute full e-tables
// e = exp(2*||row_i - row_a||) into LDS (XT reads coalesced lane->a, X_i
// wave-uniform), then b-loop via LDS float4 uniform broadcasts.
// sigmoid((d_b - d_a)/tau) = e_b / (e_b + e_a). One atomic per block.
__global__ void __launch_bounds__(192) fused_loss(const float* __restrict__ X,
                                                  const float* __restrict__ Z,
                                                  const float* __restrict__ XT,
                                                  const float* __restrict__ ZT,
                                                  float* __restrict__ out) {
    __shared__ float ex[N] __attribute__((aligned(16)));
    __shared__ float ez[N] __attribute__((aligned(16)));
    __shared__ float red[3];
    const int i = blockIdx.x >> 1;
    const int half = blockIdx.x & 1;
    const int t = threadIdx.x;

    const float* __restrict__ Xi = X + (size_t)i * DXD;   // uniform -> scalar path
    const float* __restrict__ Zi = Z + (size_t)i * DZD;

    // phase 1: full e-tables, each thread fills entries t and t+192
    #pragma unroll
    for (int rep = 0; rep < 2; ++rep) {
        const int a = rep * 192 + t;
        float sq = 0.f;
        #pragma unroll 16
        for (int k = 0; k < DXD; ++k) {
            float v = XT[(size_t)k * N + a] - Xi[k];      // coalesced across lanes
            sq += v * v;
        }
        float dx = (sq > 1e-12f) ? sqrtf(sq) : 0.f;
        ex[a] = __expf(2.f * dx);

        float sqz = 0.f;
        #pragma unroll 16
        for (int k = 0; k < DZD; ++k) {
            float v = ZT[(size_t)k * N + a] - Zi[k];
            sqz += v * v;
        }
        float dz = (sqz > 1e-12f) ? sqrtf(sqz) : 0.f;
        ez[a] = __expf(2.f * dz);
    }
    __syncthreads();

    // phase 2: b-loop, this thread's a = half*192 + t
    const int a = half * 192 + t;
    const float exa = ex[a];
    const float eza = ez[a];
    const float4* __restrict__ ex4 = reinterpret_cast<const float4*>(ex);
    const float4* __restrict__ ez4 = reinterpret_cast<const float4*>(ez);
    float sx0 = 0.f, sx1 = 0.f, sx2 = 0.f, sx3 = 0.f;
    float sz0 = 0.f, sz1 = 0.f, sz2 = 0.f, sz3 = 0.f;
    #pragma unroll 4
    for (int b = 0; b < N / 4; ++b) {
        float4 e = ex4[b];           // uniform -> LDS broadcast, conflict-free
        float4 f = ez4[b];
        sx0 += e.x * __builtin_amdgcn_rcpf(e.x + exa);
        sx1 += e.y * __builtin_amdgcn_rcpf(e.y + exa);
        sx2 += e.z * __builtin_amdgcn_rcpf(e.z + exa);
        sx3 += e.w * __builtin_amdgcn_rcpf(e.w + exa);
        sz0 += f.x * __builtin_amdgcn_rcpf(f.x + eza);
        sz1 += f.y * __builtin_amdgcn_rcpf(f.y + eza);
        sz2 += f.z * __builtin_amdgcn_rcpf(f.z + eza);
        sz3 += f.w * __builtin_amdgcn_rcpf(f.w + eza);
    }
    float sx = (sx0 + sx1) + (sx2 + sx3);
    float sz = (sz0 + sz1) + (sz2 + sz3);

    // intrusion = relu(1+sx-K); W = clamp((K+1-(1+sz))/K, 0, 1)
    float intr = fmaxf(sx - 4.f, 0.f);
    float W = fminf(fmaxf((5.f - sz) * 0.2f, 0.f), 1.f);
    float contrib = intr * (1.f - W);

    #pragma unroll
    for (int off = 32; off > 0; off >>= 1)
        contrib += __shfl_down(contrib, off, 64);
    const int lane = t & 63, w = t >> 6;
    if (lane == 0) red[w] = contrib;
    __syncthreads();
    if (t == 0) atomicAdd(out, (red[0] + red[1] + red[2]) * NORM);
}

extern "C" void kernel_launch(void* const* d_in, const int* in_sizes, int n_in,
                              void* d_out, int out_size, void* d_ws, size_t ws_size,
                              hipStream_t stream) {
    const float* X = (const float*)d_in[0];   // (384, 128) f32
    const float* Z = (const float*)d_in[1];   // (384, 32)  f32
    float* out = (float*)d_out;

    float* XT = (float*)d_ws;                  // 128*384
    float* ZT = XT + (size_t)DXD * N;          // 32*384

    transpose_xz<<<12, 256, 0, stream>>>(X, Z, XT, ZT, out);
    fused_loss<<<2 * N, 192, 0, stream>>>(X, Z, XT, ZT, out);
}